// Round 9
// baseline (307.273 us; speedup 1.0000x reference)
//
#include <hip/hip_runtime.h>
#include <hip/hip_fp16.h>
#include <cstdint>

#define GRAPHS 128

using half8 = __attribute__((ext_vector_type(8))) _Float16;
using f32x4 = __attribute__((ext_vector_type(4))) float;

__device__ __forceinline__ int lane_bcast_i(int v, int l) {
  return __builtin_amdgcn_readlane(v, l);
}
__device__ __forceinline__ float lane_bcast_f(float v, int l) {
  return __int_as_float(__builtin_amdgcn_readlane(__float_as_int(v), l));
}
__device__ __forceinline__ void load_lds16(const __half* g, __half* l) {
  __builtin_amdgcn_global_load_lds(
      (const __attribute__((address_space(1))) void*)g,
      (__attribute__((address_space(3))) void*)l, 16, 0, 0);
}
#define WAIT_VM0 __builtin_amdgcn_s_waitcnt(0x0F70)  // vmcnt(0) only

// ---------------- prep: zero + histogram + weight transpose + W·att vectors, ONE dispatch ----

__global__ __launch_bounds__(256) void k_prep(
    float* __restrict__ zbase, int zblocks,
    const int* __restrict__ ei, int E, int ET, int* __restrict__ histT, int NBK,
    const float* __restrict__ W1, __half* __restrict__ w1t,
    const float* __restrict__ W2, __half* __restrict__ w2t,
    const float* __restrict__ as1, const float* __restrict__ ad1,
    const float* __restrict__ as2, const float* __restrict__ ad2,
    int F, int HC, int LH, int wtb) {
  int b = blockIdx.x, tid = threadIdx.x;
  if (b < zblocks) {
    f32x4* p = (f32x4*)zbase + (size_t)b * 1024;  // 16KB per block
    f32x4 z = {0.f, 0.f, 0.f, 0.f};
    p[tid] = z; p[tid + 256] = z; p[tid + 512] = z; p[tid + 768] = z;
    return;
  }
  b -= zblocks;
  if (b < 256) {
    __shared__ int h[256];
    h[tid] = 0;
    __syncthreads();
    for (int e = b * 256 + tid; e < ET; e += 256 * 256) {
      int d = (e < E) ? ei[E + e] : (e - E);
      atomicAdd(&h[d >> 8], 1);
    }
    __syncthreads();
    if (tid < NBK) histT[tid * 256 + b] = h[tid];
    return;
  }
  b -= 256;
  if (b < wtb) {
    int id = b * 256 + tid;
    if (id < F * HC) {
      int nn = id / F, kk = id % F;
      w1t[(size_t)nn * F + kk] = __float2half(W1[(size_t)kk * HC + nn]);
      return;
    }
    id -= F * HC;
    if (id < HC * LH) {
      int nn = id / HC, kk = id % HC;
      w2t[(size_t)nn * HC + kk] = __float2half(W2[(size_t)kk * LH + nn]);
    }
    return;
  }
  b -= wtb;
  int s = b * 256 + tid;
  if (s < 384) {                       // L1: w_aS/w_aD per (head h, k)  rows 192+h / 195+h
    int h = s >> 7, k = s & 127;
    float sa = 0.f, sd = 0.f;
    for (int c = 0; c < 64; ++c) {
      float wv = W1[(size_t)k * HC + h * 64 + c];
      sa += wv * as1[h * 64 + c];
      sd += wv * ad1[h * 64 + c];
    }
    w1t[(size_t)(192 + h) * F + k] = __float2half(sa);
    w1t[(size_t)(195 + h) * F + k] = __float2half(sd);
  } else if (s < 576) {                // L2: rows 64 / 65
    int k = s - 384;
    float sa = 0.f, sd = 0.f;
    for (int c = 0; c < 64; ++c) {
      float wv = W2[(size_t)k * LH + c];
      sa += wv * as2[c];
      sd += wv * ad2[c];
    }
    w2t[(size_t)64 * HC + k] = __float2half(sa);
    w2t[(size_t)65 * HC + k] = __float2half(sd);
  } else {                             // zero pad rows: w1t 198-207, w2t 66-79
    int t2 = s - 576;
    for (int j = t2; j < 10 * F; j += 192) w1t[(size_t)198 * F + j] = __float2half(0.f);
    for (int j = t2; j < 14 * HC; j += 192) w2t[(size_t)66 * HC + j] = __float2half(0.f);
  }
}

// per-bucket exclusive scan over the 256 blocks
__global__ __launch_bounds__(256) void k_scan1(const int* __restrict__ histT,
                                               int* __restrict__ bexcl,
                                               int* __restrict__ total) {
  int k = blockIdx.x, tid = threadIdx.x, lane = tid & 63, wid = tid >> 6;
  int v = histT[k * 256 + tid];
  int incl = v;
#pragma unroll
  for (int o = 1; o < 64; o <<= 1) { int u = __shfl_up(incl, o); if (lane >= o) incl += u; }
  __shared__ int ws[4];
  if (lane == 63) ws[wid] = incl;
  __syncthreads();
  int woff = 0;
  for (int w = 0; w < wid; ++w) woff += ws[w];
  incl += woff;
  bexcl[k * 256 + tid] = incl - v;
  if (tid == 255) total[k] = incl;
}

// P1: partition edges into bucket-contiguous tmp; bucket starts recomputed in-LDS.
__global__ __launch_bounds__(256) void k_part(const int* __restrict__ ei, int E, int ET,
                                              const int* __restrict__ bexcl,
                                              const int* __restrict__ total,
                                              int2* __restrict__ tmp, int NBK) {
  int tid = threadIdx.x, blk = blockIdx.x, lane = tid & 63, wid = tid >> 6;
  int v = (tid < NBK) ? total[tid] : 0;
  int incl = v;
#pragma unroll
  for (int o = 1; o < 64; o <<= 1) { int u = __shfl_up(incl, o); if (lane >= o) incl += u; }
  __shared__ int ws[4];
  if (lane == 63) ws[wid] = incl;
  __syncthreads();
  int woff = 0;
  for (int w = 0; w < wid; ++w) woff += ws[w];
  incl += woff;
  __shared__ int cur[256];
  if (tid < NBK) cur[tid] = (incl - v) + bexcl[tid * 256 + blk];
  __syncthreads();
  for (int e = blk * 256 + tid; e < ET; e += 256 * 256) {
    int s, d;
    if (e < E) { s = ei[e]; d = ei[E + e]; } else { s = d = e - E; }
    int pos = atomicAdd(&cur[d >> 8], 1);
    tmp[pos] = make_int2(s, d);
  }
}

// P2: within-bucket dst-sort; bucket bounds recomputed in-LDS from total[].
__global__ __launch_bounds__(256) void k_scat2(const int2* __restrict__ tmp,
                                               const int* __restrict__ total,
                                               int2* __restrict__ epk, int NBK) {
  int k = blockIdx.x, tid = threadIdx.x, lane = tid & 63, wid = tid >> 6;
  int v = (tid < NBK) ? total[tid] : 0;
  int incl = v;
#pragma unroll
  for (int o = 1; o < 64; o <<= 1) { int u = __shfl_up(incl, o); if (lane >= o) incl += u; }
  __shared__ int ws[4];
  if (lane == 63) ws[wid] = incl;
  __syncthreads();
  int woff = 0;
  for (int w = 0; w < wid; ++w) woff += ws[w];
  incl += woff;
  __shared__ int sexc[257];
  sexc[tid] = incl - v;
  if (tid == 255) sexc[256] = incl;
  __syncthreads();
  int lo = sexc[k], hi = sexc[k + 1], n0 = k << 8;
  __shared__ int cnt[256];
  cnt[tid] = 0;
  __syncthreads();
  for (int e = lo + tid; e < hi; e += 256) atomicAdd(&cnt[tmp[e].y - n0], 1);
  __syncthreads();
  int c = cnt[tid];
  int cincl = c;
#pragma unroll
  for (int o = 1; o < 64; o <<= 1) { int u = __shfl_up(cincl, o); if (lane >= o) cincl += u; }
  __shared__ int ws2[4];
  if (lane == 63) ws2[wid] = cincl;
  __syncthreads();
  int woff2 = 0;
  for (int w = 0; w < wid; ++w) woff2 += ws2[w];
  cincl += woff2;
  __shared__ int cur[256];
  cur[tid] = lo + cincl - c;
  __syncthreads();
  for (int e = lo + tid; e < hi; e += 256) {
    int2 sd = tmp[e];
    int pos = atomicAdd(&cur[sd.y - n0], 1);
    epk[pos] = sd;
  }
}

// ---------------- MFMA GEMM: padded LDS (conflict-free), ONE barrier, direct C stores --------

template <int KT, int NH, int MODE>
__global__ __launch_bounds__(256) void k_gemm_mfma(
    const float* __restrict__ Af, const __half* __restrict__ Bth,
    __half* __restrict__ C, float* __restrict__ aS, float* __restrict__ aD,
    const float* __restrict__ bias, const float* __restrict__ dnm,
    int Ndn, int M, int NC, int ASTR) {
  constexpr int KP = KT + 8;           // +8 halves: row stride 272/400B == 4 banks -> 2-way
  constexpr int K8 = KT / 8;
  constexpr int KS = KT / 32;
  __shared__ __align__(16) _Float16 Asm[64 * KP];
  int tid = threadIdx.x;
  int w = tid >> 6, lane = tid & 63;
  int col = lane & 15, quad = lane >> 4;
  int m0 = blockIdx.x * 64;
  const half8* B8 = (const half8*)Bth;
  half8 bfa[NH][KS];
#pragma unroll
  for (int h = 0; h < NH; ++h) {
    int n0w = h * 64 + w * 16;
#pragma unroll
    for (int s = 0; s < KS; ++s) bfa[h][s] = B8[(size_t)(n0w + col) * K8 + s * 4 + quad];
  }
  half8 bfx[KS];
  if (w == 0) {                        // fold-column tile (aS/aD)
    int nx = NH * 64 + col;
#pragma unroll
    for (int s = 0; s < KS; ++s) bfx[s] = B8[(size_t)nx * K8 + s * 4 + quad];
  }
  for (int i = tid; i < 64 * K8; i += 256) {
    int row = i / K8, c8 = i % K8;
    int gm = min(m0 + row, M - 1);
    const float* src = Af + (size_t)gm * KT + c8 * 8;
    float4 v0 = *(const float4*)src;
    float4 v1 = *(const float4*)(src + 4);
    float o[8] = {v0.x, v0.y, v0.z, v0.w, v1.x, v1.y, v1.z, v1.w};
    if (MODE == 1) {
      int c = c8 * 8;
      float inv = 1.0f / fmaxf(dnm[(size_t)(c8 >> 3) * Ndn + gm], 1e-16f);
#pragma unroll
      for (int k = 0; k < 8; ++k) {
        float t = o[k] * inv + bias[c + k];
        o[k] = t > 0.f ? t : __expf(t) - 1.f;
      }
    }
    half8 h;
#pragma unroll
    for (int k = 0; k < 8; ++k) h[k] = (_Float16)o[k];
    *(half8*)&Asm[(size_t)row * KP + c8 * 8] = h;
  }
  __syncthreads();                     // the ONLY barrier
#pragma unroll
  for (int h = 0; h < NH; ++h) {
#pragma unroll
    for (int i = 0; i < 4; ++i) {
      f32x4 acc = {0.f, 0.f, 0.f, 0.f};
#pragma unroll
      for (int s = 0; s < KS; ++s) {
        half8 a = *(const half8*)&Asm[(i * 16 + col) * KP + s * 32 + quad * 8];
        acc = __builtin_amdgcn_mfma_f32_16x16x32_f16(a, bfa[h][s], acc, 0, 0, 0);
      }
#pragma unroll
      for (int r = 0; r < 4; ++r) {
        int gm = m0 + i * 16 + quad * 4 + r;
        if (gm < M) C[(size_t)gm * NC + h * 64 + w * 16 + col] = (_Float16)acc[r];
      }
    }
  }
  if (w == 0) {
#pragma unroll
    for (int i = 0; i < 4; ++i) {
      f32x4 acc = {0.f, 0.f, 0.f, 0.f};
#pragma unroll
      for (int s = 0; s < KS; ++s) {
        half8 a = *(const half8*)&Asm[(i * 16 + col) * KP + s * 32 + quad * 8];
        acc = __builtin_amdgcn_mfma_f32_16x16x32_f16(a, bfx[s], acc, 0, 0, 0);
      }
#pragma unroll
      for (int r = 0; r < 4; ++r) {
        int gm = m0 + i * 16 + quad * 4 + r;
        if (gm < M) {
          if (col < NH) aS[(size_t)gm * ASTR + col] = acc[r];
          else if (col < 2 * NH) aD[(size_t)gm * ASTR + (col - NH)] = acc[r];
        }
      }
    }
  }
}

// ---------------- edge-parallel aggregation, 64-edge chunks, interior plain stores ----------
// head passed as ARGUMENT: L1 runs as 3 independent per-head dispatches this round so the
// profiler's top-5 window (threshold drops 72 -> ~26us) exposes the mid-tier kernels.

template <int NH>
__global__ __launch_bounds__(256) void k_aggE(
    const int2* __restrict__ ep,
    const float* __restrict__ aS, const float* __restrict__ aD,
    const __half* __restrict__ xp, float* __restrict__ outf, float* __restrict__ dnm,
    int ET, int rowstr, int ostr, int Ndn, int head) {
  __shared__ __half stage[4][4096];
  int wv = (blockIdx.x * 256 + (int)threadIdx.x) >> 6;
  int lane = threadIdx.x & 63;
  int wid = (threadIdx.x >> 6) & 3;
  __half* st = stage[wid];
  int coloff = head * 64;
  int e0 = wv * 64;
  if (e0 >= ET) return;
  int j = e0 + lane;
  int jc = min(j, ET - 1);
  int2 sd = ep[jc];                            // coalesced 8B
  int sreg = sd.x, dstv = sd.y;
  float dd = 0.f;
  if (NH == 3) {
    float4 a4 = *(const float4*)&aS[(size_t)sreg * 4];   // random 16B, L2-resident
    float4 b4 = *(const float4*)&aD[(size_t)dstv * 4];   // dst-sorted -> near-coalesced
    float v = (head == 0) ? (a4.x + b4.x) : ((head == 1) ? (a4.y + b4.y) : (a4.z + b4.z));
    v = v > 0.f ? v : 0.2f * v;
    dd = __expf(v);
  } else {
    float v = aS[sreg] + aD[dstv];
    v = v > 0.f ? v : 0.2f * v;
    dd = __expf(v);
  }
  if (j >= ET) dd = 0.f;
#pragma unroll
  for (int k = 0; k < 8; ++k) {
    int src = __shfl(sreg, k * 8 + (lane >> 3));
    const __half* g = xp + (size_t)src * rowstr + coloff + (lane & 7) * 8;
    load_lds16(g, st + k * 512);               // 8 rows of 64 halves per DMA
  }
  int dn = __shfl_down(dstv, 1);
  unsigned long long bmask = __ballot(lane == 63 || dn != dstv);  // segment-end lanes
  WAIT_VM0;                                    // the only wait in the wave's lifetime
  float acc = 0.f, dsum = 0.f;
  int dcur = lane_bcast_i(dstv, 0);
  int segstart = 0;
#pragma unroll 4
  for (int u = 0; u < 64; ++u) {
    float c = lane_bcast_f(dd, u);
    acc = fmaf(c, __half2float(st[(u >> 3) * 512 + (u & 7) * 64 + lane]), acc);
    dsum += c;
    if ((bmask >> u) & 1ull) {                 // wave-uniform scalar test
      size_t op = (size_t)dcur * ostr + coloff + lane;
      if (segstart > 0 && u < 63) {            // complete segment: plain store
        outf[op] = acc;
        if (lane == 0) dnm[(size_t)head * Ndn + dcur] = dsum;
      } else {                                 // chunk-boundary segment: atomic
        atomicAdd(&outf[op], acc);
        if (lane == 0) atomicAdd(&dnm[(size_t)head * Ndn + dcur], dsum);
      }
      acc = 0.f; dsum = 0.f; segstart = u + 1;
      if (u < 63) dcur = lane_bcast_i(dstv, u + 1);
    }
  }
}

// ---------------- fused pooling + final linear (one block per graph, NO atomics) ------------

__global__ __launch_bounds__(256) void k_poolfinal(
    const float* __restrict__ h2f, const float* __restrict__ dnm2,
    const int* __restrict__ batch, const float* __restrict__ b2,
    const float* __restrict__ lw, const float* __restrict__ lb,
    float* __restrict__ out, int N) {
  int g = blockIdx.x;
  __shared__ int sse[2];
  __shared__ float red[4][64];
  if (threadIdx.x < 2) {
    int target = g + (int)threadIdx.x;
    int lo = 0, hi = N;
    while (lo < hi) { int mid = (lo + hi) >> 1; if (batch[mid] < target) lo = mid + 1; else hi = mid; }
    sse[threadIdx.x] = lo;
  }
  __syncthreads();
  int start = sse[0], end = sse[1];
  int lane = threadIdx.x & 63, wid = threadIdx.x >> 6;
  float acc = 0.f;
  for (int n = start + wid; n < end; n += 4) {
    float inv = 1.0f / fmaxf(dnm2[n], 1e-16f);
    acc = fmaf(h2f[(size_t)n * 64 + lane], inv, acc);
  }
  red[wid][lane] = acc;
  __syncthreads();
  if (wid == 0) {
    float inv = 1.0f / fmaxf((float)(end - start), 1.0f);
    float pv = (red[0][lane] + red[1][lane] + red[2][lane] + red[3][lane]) * inv + b2[lane];
#pragma unroll
    for (int k = 0; k < 10; ++k) {
      float v = pv * lw[lane * 10 + k];
#pragma unroll
      for (int o = 1; o < 64; o <<= 1) v += __shfl_xor(v, o);
      if (lane == 0) out[g * 10 + k] = v + lb[k];
    }
  }
}

extern "C" void kernel_launch(void* const* d_in, const int* in_sizes, int n_in,
                              void* d_out, int out_size, void* d_ws, size_t ws_size,
                              hipStream_t stream) {
  const float* x = (const float*)d_in[0];
  const int* ei = (const int*)d_in[1];
  const int* batch = (const int*)d_in[2];
  const float* W1 = (const float*)d_in[3];
  const float* as1 = (const float*)d_in[4];
  const float* ad1 = (const float*)d_in[5];
  const float* b1 = (const float*)d_in[6];
  const float* W2 = (const float*)d_in[7];
  const float* as2 = (const float*)d_in[8];
  const float* ad2 = (const float*)d_in[9];
  const float* b2 = (const float*)d_in[10];
  const float* lw = (const float*)d_in[11];
  const float* lb = (const float*)d_in[12];
  float* out = (float*)d_out;

  const int N = in_sizes[2];        // 50000
  const int E = in_sizes[1] / 2;    // 800000
  const int ET = E + N;             // + self loops
  const int F = in_sizes[0] / N;    // 128
  const int HC = in_sizes[6];       // 192
  const int LH = in_sizes[10];      // 64
  const int NBK = (N + 255) >> 8;   // 196 node-buckets (<=256 required)

  size_t off = 0;
  auto alo = [&](size_t bytes) -> char* {
    char* p = (char*)d_ws + off;
    off += (bytes + 255) & ~(size_t)255;
    return p;
  };
  float* h1f = (float*)alo((size_t)N * 192 * 4);    // fp32 unnormalized numerators
  float* h2f = (float*)alo((size_t)N * 64 * 4);
  float* dnm1 = (float*)alo((size_t)3 * N * 4);     // softmax denominators [head][node]
  float* dnm2 = (float*)alo((size_t)N * 4);
  size_t zbytes = off;                              // zero everything above
  float* aS1 = (float*)alo((size_t)N * 4 * 4);      // direct-stored by GEMM (zero-overrun ok)
  float* aD1 = (float*)alo((size_t)N * 4 * 4);
  float* aS2 = (float*)alo((size_t)N * 4);
  float* aD2 = (float*)alo((size_t)N * 4);
  int* histT = (int*)alo((size_t)256 * 256 * 4);
  int* bexcl = (int*)alo((size_t)256 * 256 * 4);
  int* total = (int*)alo((size_t)256 * 4);
  int2* tmp = (int2*)alo((size_t)ET * 8);           // bucket-partitioned edges
  int2* epk = (int2*)alo((size_t)ET * 8);           // final dst-sorted (src,dst)
  __half* w1t = (__half*)alo((size_t)208 * F * 2);  // rows 0-191 W1^T, 192-197 W·att, 198-207 pad0
  __half* w2t = (__half*)alo((size_t)80 * HC * 2);  // rows 0-63 W2^T, 64-65 W·att, 66-79 pad0
  __half* xp1 = (__half*)alo((size_t)N * 192 * 2 + 512);  // +pad: DMA clamp overreach
  __half* xp2 = (__half*)alo((size_t)N * 64 * 2 + 512);

  // ---- prep (zero + hist + wt + W·att) -> scan -> partition -> in-bucket sort ----
  int zb = (int)((zbytes + 16383) / 16384);         // 16KB zero tiles (overrun into aS1 ok)
  int wtTot = F * HC + HC * LH;
  int wtb = (wtTot + 255) / 256;
  k_prep<<<zb + 256 + wtb + 3, 256, 0, stream>>>((float*)d_ws, zb, ei, E, ET, histT, NBK,
                                                 W1, w1t, W2, w2t, as1, ad1, as2, ad2,
                                                 F, HC, LH, wtb);
  k_scan1<<<NBK, 256, 0, stream>>>(histT, bexcl, total);
  k_part<<<256, 256, 0, stream>>>(ei, E, ET, bexcl, total, tmp, NBK);
  k_scat2<<<NBK, 256, 0, stream>>>(tmp, total, epk, NBK);

  int mb = (N + 63) / 64;
  int wavesE = (ET + 63) / 64;
  int ebk = (wavesE + 3) / 4;

  // ---- layer 1: MFMA GEMM -> per-head agg dispatches (visibility round) ----
  k_gemm_mfma<128, 3, 0><<<mb, 256, 0, stream>>>(x, w1t, xp1, aS1, aD1,
                                                 nullptr, nullptr, 0, N, HC, 4);
  k_aggE<3><<<ebk, 256, 0, stream>>>(epk, aS1, aD1, xp1, h1f, dnm1, ET, 192, 192, N, 0);
  k_aggE<3><<<ebk, 256, 0, stream>>>(epk, aS1, aD1, xp1, h1f, dnm1, ET, 192, 192, N, 1);
  k_aggE<3><<<ebk, 256, 0, stream>>>(epk, aS1, aD1, xp1, h1f, dnm1, ET, 192, 192, N, 2);
  // ---- layer 2: MFMA GEMM (A = h1f/denom + bias + ELU) -> agg -> pool+final ----
  k_gemm_mfma<192, 1, 1><<<mb, 256, 0, stream>>>(h1f, w2t, xp2, aS2, aD2,
                                                 b1, dnm1, N, N, LH, 1);
  k_aggE<1><<<ebk, 256, 0, stream>>>(epk, aS2, aD2, xp2, h2f, dnm2, ET, 64, 64, N, 0);
  k_poolfinal<<<GRAPHS, 256, 0, stream>>>(h2f, dnm2, batch, b2, lw, lb, out, N);
}

// Round 11
// 273.236 us; speedup vs baseline: 1.1246x; 1.1246x over previous
//
#include <hip/hip_runtime.h>
#include <hip/hip_fp16.h>
#include <cstdint>

#define GRAPHS 128

using half8 = __attribute__((ext_vector_type(8))) _Float16;
using f32x4 = __attribute__((ext_vector_type(4))) float;

__device__ __forceinline__ int lane_bcast_i(int v, int l) {
  return __builtin_amdgcn_readlane(v, l);
}
__device__ __forceinline__ float lane_bcast_f(float v, int l) {
  return __int_as_float(__builtin_amdgcn_readlane(__float_as_int(v), l));
}
__device__ __forceinline__ void load_lds16(const __half* g, __half* l) {
  __builtin_amdgcn_global_load_lds(
      (const __attribute__((address_space(1))) void*)g,
      (__attribute__((address_space(3))) void*)l, 16, 0, 0);
}
#define WAIT_VM0 __builtin_amdgcn_s_waitcnt(0x0F70)  // vmcnt(0) only

// ---------------- prep: zero + histogram + weight transpose + W·att vectors, ONE dispatch ----

__global__ __launch_bounds__(256) void k_prep(
    float* __restrict__ zbase, int zblocks,
    const int* __restrict__ ei, int E, int ET, int* __restrict__ histT, int NBK,
    const float* __restrict__ W1, __half* __restrict__ w1t,
    const float* __restrict__ W2, __half* __restrict__ w2t,
    const float* __restrict__ as1, const float* __restrict__ ad1,
    const float* __restrict__ as2, const float* __restrict__ ad2,
    int F, int HC, int LH, int wtb) {
  int b = blockIdx.x, tid = threadIdx.x;
  if (b < zblocks) {
    f32x4* p = (f32x4*)zbase + (size_t)b * 1024;  // 16KB per block
    f32x4 z = {0.f, 0.f, 0.f, 0.f};
    p[tid] = z; p[tid + 256] = z; p[tid + 512] = z; p[tid + 768] = z;
    return;
  }
  b -= zblocks;
  if (b < 256) {
    __shared__ int h[256];
    h[tid] = 0;
    __syncthreads();
    for (int e = b * 256 + tid; e < ET; e += 256 * 256) {
      int d = (e < E) ? ei[E + e] : (e - E);
      atomicAdd(&h[d >> 8], 1);
    }
    __syncthreads();
    if (tid < NBK) histT[tid * 256 + b] = h[tid];
    return;
  }
  b -= 256;
  if (b < wtb) {
    int id = b * 256 + tid;
    if (id < F * HC) {
      int nn = id / F, kk = id % F;
      w1t[(size_t)nn * F + kk] = __float2half(W1[(size_t)kk * HC + nn]);
      return;
    }
    id -= F * HC;
    if (id < HC * LH) {
      int nn = id / HC, kk = id % HC;
      w2t[(size_t)nn * HC + kk] = __float2half(W2[(size_t)kk * LH + nn]);
    }
    return;
  }
  b -= wtb;
  int s = b * 256 + tid;
  if (s < 384) {                       // L1: w_aS/w_aD per (head h, k)  rows 192+h / 195+h
    int h = s >> 7, k = s & 127;
    float sa = 0.f, sd = 0.f;
    for (int c = 0; c < 64; ++c) {
      float wv = W1[(size_t)k * HC + h * 64 + c];
      sa += wv * as1[h * 64 + c];
      sd += wv * ad1[h * 64 + c];
    }
    w1t[(size_t)(192 + h) * F + k] = __float2half(sa);
    w1t[(size_t)(195 + h) * F + k] = __float2half(sd);
  } else if (s < 576) {                // L2: rows 64 / 65
    int k = s - 384;
    float sa = 0.f, sd = 0.f;
    for (int c = 0; c < 64; ++c) {
      float wv = W2[(size_t)k * LH + c];
      sa += wv * as2[c];
      sd += wv * ad2[c];
    }
    w2t[(size_t)64 * HC + k] = __float2half(sa);
    w2t[(size_t)65 * HC + k] = __float2half(sd);
  } else {                             // zero pad rows: w1t 198-207, w2t 66-79
    int t2 = s - 576;
    for (int j = t2; j < 10 * F; j += 192) w1t[(size_t)198 * F + j] = __float2half(0.f);
    for (int j = t2; j < 14 * HC; j += 192) w2t[(size_t)66 * HC + j] = __float2half(0.f);
  }
}

// per-bucket exclusive scan over the 256 blocks
__global__ __launch_bounds__(256) void k_scan1(const int* __restrict__ histT,
                                               int* __restrict__ bexcl,
                                               int* __restrict__ total) {
  int k = blockIdx.x, tid = threadIdx.x, lane = tid & 63, wid = tid >> 6;
  int v = histT[k * 256 + tid];
  int incl = v;
#pragma unroll
  for (int o = 1; o < 64; o <<= 1) { int u = __shfl_up(incl, o); if (lane >= o) incl += u; }
  __shared__ int ws[4];
  if (lane == 63) ws[wid] = incl;
  __syncthreads();
  int woff = 0;
  for (int w = 0; w < wid; ++w) woff += ws[w];
  incl += woff;
  bexcl[k * 256 + tid] = incl - v;
  if (tid == 255) total[k] = incl;
}

// P1: partition edges into bucket-contiguous tmp; bucket starts recomputed in-LDS.
__global__ __launch_bounds__(256) void k_part(const int* __restrict__ ei, int E, int ET,
                                              const int* __restrict__ bexcl,
                                              const int* __restrict__ total,
                                              int2* __restrict__ tmp, int NBK) {
  int tid = threadIdx.x, blk = blockIdx.x, lane = tid & 63, wid = tid >> 6;
  int v = (tid < NBK) ? total[tid] : 0;
  int incl = v;
#pragma unroll
  for (int o = 1; o < 64; o <<= 1) { int u = __shfl_up(incl, o); if (lane >= o) incl += u; }
  __shared__ int ws[4];
  if (lane == 63) ws[wid] = incl;
  __syncthreads();
  int woff = 0;
  for (int w = 0; w < wid; ++w) woff += ws[w];
  incl += woff;
  __shared__ int cur[256];
  if (tid < NBK) cur[tid] = (incl - v) + bexcl[tid * 256 + blk];
  __syncthreads();
  for (int e = blk * 256 + tid; e < ET; e += 256 * 256) {
    int s, d;
    if (e < E) { s = ei[e]; d = ei[E + e]; } else { s = d = e - E; }
    int pos = atomicAdd(&cur[d >> 8], 1);
    tmp[pos] = make_int2(s, d);
  }
}

// ---------------- FUSED: in-bucket dst-sort (blocks [0,NBK)) ∥ L1 MFMA GEMM (rest) ----------
// scat2 depends only on k_part; GEMM1 depends only on k_prep -> they are independent and
// run concurrently in one dispatch, removing ~gemm1's serial latency from the critical path.

template <int KT, int NH, int MODE>
__global__ __launch_bounds__(256) void k_scatgemm(
    const int2* __restrict__ tmp, const int* __restrict__ total,
    int2* __restrict__ epk, int NBK,
    const float* __restrict__ Af, const __half* __restrict__ Bth,
    __half* __restrict__ C, float* __restrict__ aS, float* __restrict__ aD,
    const float* __restrict__ bias, const float* __restrict__ dnm,
    int Ndn, int M, int NC, int ASTR) {
  int tid = threadIdx.x;
  int lane = tid & 63, wid4 = tid >> 6;
  if ((int)blockIdx.x < NBK) {         // ---------- scat2 path ----------
    int k = blockIdx.x;
    int v = (tid < NBK) ? total[tid] : 0;
    int incl = v;
#pragma unroll
    for (int o = 1; o < 64; o <<= 1) { int u = __shfl_up(incl, o); if (lane >= o) incl += u; }
    __shared__ int ws[4];
    if (lane == 63) ws[wid4] = incl;
    __syncthreads();
    int woff = 0;
    for (int w = 0; w < wid4; ++w) woff += ws[w];
    incl += woff;
    __shared__ int sexc[257];
    sexc[tid] = incl - v;
    if (tid == 255) sexc[256] = incl;
    __syncthreads();
    int lo = sexc[k], hi = sexc[k + 1], n0 = k << 8;
    __shared__ int cnt[256];
    cnt[tid] = 0;
    __syncthreads();
    for (int e = lo + tid; e < hi; e += 256) atomicAdd(&cnt[tmp[e].y - n0], 1);
    __syncthreads();
    int c = cnt[tid];
    int cincl = c;
#pragma unroll
    for (int o = 1; o < 64; o <<= 1) { int u = __shfl_up(cincl, o); if (lane >= o) cincl += u; }
    __shared__ int ws2[4];
    if (lane == 63) ws2[wid4] = cincl;
    __syncthreads();
    int woff2 = 0;
    for (int w = 0; w < wid4; ++w) woff2 += ws2[w];
    cincl += woff2;
    __shared__ int cur[256];
    cur[tid] = lo + cincl - c;
    __syncthreads();
    for (int e = lo + tid; e < hi; e += 256) {
      int2 sd = tmp[e];
      int pos = atomicAdd(&cur[sd.y - n0], 1);
      epk[pos] = sd;
    }
    return;
  }
  // ---------- GEMM path (padded LDS, one barrier, fold-column aS/aD) ----------
  constexpr int KP = KT + 8;           // +8 halves: 2-way banks only
  constexpr int K8 = KT / 8;
  constexpr int KS = KT / 32;
  __shared__ __align__(16) _Float16 Asm[64 * KP];
  int w = tid >> 6;
  int col = lane & 15, quad = lane >> 4;
  int m0 = ((int)blockIdx.x - NBK) * 64;
  const half8* B8 = (const half8*)Bth;
  half8 bfa[NH][KS];
#pragma unroll
  for (int h = 0; h < NH; ++h) {
    int n0w = h * 64 + w * 16;
#pragma unroll
    for (int s = 0; s < KS; ++s) bfa[h][s] = B8[(size_t)(n0w + col) * K8 + s * 4 + quad];
  }
  half8 bfx[KS];
  if (w == 0) {                        // fold-column tile (aS/aD)
    int nx = NH * 64 + col;
#pragma unroll
    for (int s = 0; s < KS; ++s) bfx[s] = B8[(size_t)nx * K8 + s * 4 + quad];
  }
  for (int i = tid; i < 64 * K8; i += 256) {
    int row = i / K8, c8 = i % K8;
    int gm = min(m0 + row, M - 1);
    const float* src = Af + (size_t)gm * KT + c8 * 8;
    float4 v0 = *(const float4*)src;
    float4 v1 = *(const float4*)(src + 4);
    float o[8] = {v0.x, v0.y, v0.z, v0.w, v1.x, v1.y, v1.z, v1.w};
    if (MODE == 1) {
      int c = c8 * 8;
      float inv = 1.0f / fmaxf(dnm[(size_t)(c8 >> 3) * Ndn + gm], 1e-16f);
#pragma unroll
      for (int k = 0; k < 8; ++k) {
        float t = o[k] * inv + bias[c + k];
        o[k] = t > 0.f ? t : __expf(t) - 1.f;
      }
    }
    half8 h;
#pragma unroll
    for (int k = 0; k < 8; ++k) h[k] = (_Float16)o[k];
    *(half8*)&Asm[(size_t)row * KP + c8 * 8] = h;
  }
  __syncthreads();                     // the ONLY barrier
#pragma unroll
  for (int h = 0; h < NH; ++h) {
#pragma unroll
    for (int i = 0; i < 4; ++i) {
      f32x4 acc = {0.f, 0.f, 0.f, 0.f};
#pragma unroll
      for (int s = 0; s < KS; ++s) {
        half8 a = *(const half8*)&Asm[(i * 16 + col) * KP + s * 32 + quad * 8];
        acc = __builtin_amdgcn_mfma_f32_16x16x32_f16(a, bfa[h][s], acc, 0, 0, 0);
      }
#pragma unroll
      for (int r = 0; r < 4; ++r) {
        int gm = m0 + i * 16 + quad * 4 + r;
        if (gm < M) C[(size_t)gm * NC + h * 64 + w * 16 + col] = (_Float16)acc[r];
      }
    }
  }
  if (w == 0) {
#pragma unroll
    for (int i = 0; i < 4; ++i) {
      f32x4 acc = {0.f, 0.f, 0.f, 0.f};
#pragma unroll
      for (int s = 0; s < KS; ++s) {
        half8 a = *(const half8*)&Asm[(i * 16 + col) * KP + s * 32 + quad * 8];
        acc = __builtin_amdgcn_mfma_f32_16x16x32_f16(a, bfx[s], acc, 0, 0, 0);
      }
#pragma unroll
      for (int r = 0; r < 4; ++r) {
        int gm = m0 + i * 16 + quad * 4 + r;
        if (gm < M) {
          if (col < NH) aS[(size_t)gm * ASTR + col] = acc[r];
          else if (col < 2 * NH) aD[(size_t)gm * ASTR + (col - NH)] = acc[r];
        }
      }
    }
  }
}

// ---------------- standalone GEMM (layer 2) ----------------

template <int KT, int NH, int MODE>
__global__ __launch_bounds__(256) void k_gemm_mfma(
    const float* __restrict__ Af, const __half* __restrict__ Bth,
    __half* __restrict__ C, float* __restrict__ aS, float* __restrict__ aD,
    const float* __restrict__ bias, const float* __restrict__ dnm,
    int Ndn, int M, int NC, int ASTR) {
  constexpr int KP = KT + 8;
  constexpr int K8 = KT / 8;
  constexpr int KS = KT / 32;
  __shared__ __align__(16) _Float16 Asm[64 * KP];
  int tid = threadIdx.x;
  int w = tid >> 6, lane = tid & 63;
  int col = lane & 15, quad = lane >> 4;
  int m0 = blockIdx.x * 64;
  const half8* B8 = (const half8*)Bth;
  half8 bfa[NH][KS];
#pragma unroll
  for (int h = 0; h < NH; ++h) {
    int n0w = h * 64 + w * 16;
#pragma unroll
    for (int s = 0; s < KS; ++s) bfa[h][s] = B8[(size_t)(n0w + col) * K8 + s * 4 + quad];
  }
  half8 bfx[KS];
  if (w == 0) {
    int nx = NH * 64 + col;
#pragma unroll
    for (int s = 0; s < KS; ++s) bfx[s] = B8[(size_t)nx * K8 + s * 4 + quad];
  }
  for (int i = tid; i < 64 * K8; i += 256) {
    int row = i / K8, c8 = i % K8;
    int gm = min(m0 + row, M - 1);
    const float* src = Af + (size_t)gm * KT + c8 * 8;
    float4 v0 = *(const float4*)src;
    float4 v1 = *(const float4*)(src + 4);
    float o[8] = {v0.x, v0.y, v0.z, v0.w, v1.x, v1.y, v1.z, v1.w};
    if (MODE == 1) {
      int c = c8 * 8;
      float inv = 1.0f / fmaxf(dnm[(size_t)(c8 >> 3) * Ndn + gm], 1e-16f);
#pragma unroll
      for (int k = 0; k < 8; ++k) {
        float t = o[k] * inv + bias[c + k];
        o[k] = t > 0.f ? t : __expf(t) - 1.f;
      }
    }
    half8 h;
#pragma unroll
    for (int k = 0; k < 8; ++k) h[k] = (_Float16)o[k];
    *(half8*)&Asm[(size_t)row * KP + c8 * 8] = h;
  }
  __syncthreads();
#pragma unroll
  for (int h = 0; h < NH; ++h) {
#pragma unroll
    for (int i = 0; i < 4; ++i) {
      f32x4 acc = {0.f, 0.f, 0.f, 0.f};
#pragma unroll
      for (int s = 0; s < KS; ++s) {
        half8 a = *(const half8*)&Asm[(i * 16 + col) * KP + s * 32 + quad * 8];
        acc = __builtin_amdgcn_mfma_f32_16x16x32_f16(a, bfa[h][s], acc, 0, 0, 0);
      }
#pragma unroll
      for (int r = 0; r < 4; ++r) {
        int gm = m0 + i * 16 + quad * 4 + r;
        if (gm < M) C[(size_t)gm * NC + h * 64 + w * 16 + col] = (_Float16)acc[r];
      }
    }
  }
  if (w == 0) {
#pragma unroll
    for (int i = 0; i < 4; ++i) {
      f32x4 acc = {0.f, 0.f, 0.f, 0.f};
#pragma unroll
      for (int s = 0; s < KS; ++s) {
        half8 a = *(const half8*)&Asm[(i * 16 + col) * KP + s * 32 + quad * 8];
        acc = __builtin_amdgcn_mfma_f32_16x16x32_f16(a, bfx[s], acc, 0, 0, 0);
      }
#pragma unroll
      for (int r = 0; r < 4; ++r) {
        int gm = m0 + i * 16 + quad * 4 + r;
        if (gm < M) {
          if (col < NH) aS[(size_t)gm * ASTR + col] = acc[r];
          else if (col < 2 * NH) aD[(size_t)gm * ASTR + (col - NH)] = acc[r];
        }
      }
    }
  }
}

// ---------------- edge-parallel aggregation, 64-edge chunks, interior plain stores ----------

template <int NH>
__global__ __launch_bounds__(256) void k_aggE(
    const int2* __restrict__ ep,
    const float* __restrict__ aS, const float* __restrict__ aD,
    const __half* __restrict__ xp, float* __restrict__ outf, float* __restrict__ dnm,
    int ET, int rowstr, int ostr, int Ndn) {
  __shared__ __half stage[4][4096];
  int wv = (blockIdx.x * 256 + (int)threadIdx.x) >> 6;
  int lane = threadIdx.x & 63;
  int wid = (threadIdx.x >> 6) & 3;
  __half* st = stage[wid];
  int head = blockIdx.y;
  int coloff = head * 64;
  int e0 = wv * 64;
  if (e0 >= ET) return;
  int j = e0 + lane;
  int jc = min(j, ET - 1);
  int2 sd = ep[jc];                            // coalesced 8B
  int sreg = sd.x, dstv = sd.y;
  float dd = 0.f;
  if (NH == 3) {
    float4 a4 = *(const float4*)&aS[(size_t)sreg * 4];   // random 16B, L2-resident
    float4 b4 = *(const float4*)&aD[(size_t)dstv * 4];   // dst-sorted -> near-coalesced
    float v = (head == 0) ? (a4.x + b4.x) : ((head == 1) ? (a4.y + b4.y) : (a4.z + b4.z));
    v = v > 0.f ? v : 0.2f * v;
    dd = __expf(v);
  } else {
    float v = aS[sreg] + aD[dstv];
    v = v > 0.f ? v : 0.2f * v;
    dd = __expf(v);
  }
  if (j >= ET) dd = 0.f;
#pragma unroll
  for (int k = 0; k < 8; ++k) {
    int src = __shfl(sreg, k * 8 + (lane >> 3));
    const __half* g = xp + (size_t)src * rowstr + coloff + (lane & 7) * 8;
    load_lds16(g, st + k * 512);               // 8 rows of 64 halves per DMA
  }
  int dn = __shfl_down(dstv, 1);
  unsigned long long bmask = __ballot(lane == 63 || dn != dstv);  // segment-end lanes
  WAIT_VM0;                                    // the only wait in the wave's lifetime
  float acc = 0.f, dsum = 0.f;
  int dcur = lane_bcast_i(dstv, 0);
  int segstart = 0;
#pragma unroll 4
  for (int u = 0; u < 64; ++u) {
    float c = lane_bcast_f(dd, u);
    acc = fmaf(c, __half2float(st[(u >> 3) * 512 + (u & 7) * 64 + lane]), acc);
    dsum += c;
    if ((bmask >> u) & 1ull) {                 // wave-uniform scalar test
      size_t op = (size_t)dcur * ostr + coloff + lane;
      if (segstart > 0 && u < 63) {            // complete segment: plain store
        outf[op] = acc;
        if (lane == 0) dnm[(size_t)head * Ndn + dcur] = dsum;
      } else {                                 // chunk-boundary segment: atomic
        atomicAdd(&outf[op], acc);
        if (lane == 0) atomicAdd(&dnm[(size_t)head * Ndn + dcur], dsum);
      }
      acc = 0.f; dsum = 0.f; segstart = u + 1;
      if (u < 63) dcur = lane_bcast_i(dstv, u + 1);
    }
  }
}

// ---------------- fused pooling + final linear (one block per graph, NO atomics) ------------

__global__ __launch_bounds__(256) void k_poolfinal(
    const float* __restrict__ h2f, const float* __restrict__ dnm2,
    const int* __restrict__ batch, const float* __restrict__ b2,
    const float* __restrict__ lw, const float* __restrict__ lb,
    float* __restrict__ out, int N) {
  int g = blockIdx.x;
  __shared__ int sse[2];
  __shared__ float red[4][64];
  if (threadIdx.x < 2) {
    int target = g + (int)threadIdx.x;
    int lo = 0, hi = N;
    while (lo < hi) { int mid = (lo + hi) >> 1; if (batch[mid] < target) lo = mid + 1; else hi = mid; }
    sse[threadIdx.x] = lo;
  }
  __syncthreads();
  int start = sse[0], end = sse[1];
  int lane = threadIdx.x & 63, wid = threadIdx.x >> 6;
  float acc = 0.f;
  for (int n = start + wid; n < end; n += 4) {
    float inv = 1.0f / fmaxf(dnm2[n], 1e-16f);
    acc = fmaf(h2f[(size_t)n * 64 + lane], inv, acc);
  }
  red[wid][lane] = acc;
  __syncthreads();
  if (wid == 0) {
    float inv = 1.0f / fmaxf((float)(end - start), 1.0f);
    float pv = (red[0][lane] + red[1][lane] + red[2][lane] + red[3][lane]) * inv + b2[lane];
#pragma unroll
    for (int k = 0; k < 10; ++k) {
      float v = pv * lw[lane * 10 + k];
#pragma unroll
      for (int o = 1; o < 64; o <<= 1) v += __shfl_xor(v, o);
      if (lane == 0) out[g * 10 + k] = v + lb[k];
    }
  }
}

extern "C" void kernel_launch(void* const* d_in, const int* in_sizes, int n_in,
                              void* d_out, int out_size, void* d_ws, size_t ws_size,
                              hipStream_t stream) {
  const float* x = (const float*)d_in[0];
  const int* ei = (const int*)d_in[1];
  const int* batch = (const int*)d_in[2];
  const float* W1 = (const float*)d_in[3];
  const float* as1 = (const float*)d_in[4];
  const float* ad1 = (const float*)d_in[5];
  const float* b1 = (const float*)d_in[6];
  const float* W2 = (const float*)d_in[7];
  const float* as2 = (const float*)d_in[8];
  const float* ad2 = (const float*)d_in[9];
  const float* b2 = (const float*)d_in[10];
  const float* lw = (const float*)d_in[11];
  const float* lb = (const float*)d_in[12];
  float* out = (float*)d_out;

  const int N = in_sizes[2];        // 50000
  const int E = in_sizes[1] / 2;    // 800000
  const int ET = E + N;             // + self loops
  const int F = in_sizes[0] / N;    // 128
  const int HC = in_sizes[6];       // 192
  const int LH = in_sizes[10];      // 64
  const int NBK = (N + 255) >> 8;   // 196 node-buckets (<=256 required)

  size_t off = 0;
  auto alo = [&](size_t bytes) -> char* {
    char* p = (char*)d_ws + off;
    off += (bytes + 255) & ~(size_t)255;
    return p;
  };
  float* h1f = (float*)alo((size_t)N * 192 * 4);    // fp32 unnormalized numerators
  float* h2f = (float*)alo((size_t)N * 64 * 4);
  float* dnm1 = (float*)alo((size_t)3 * N * 4);     // softmax denominators [head][node]
  float* dnm2 = (float*)alo((size_t)N * 4);
  size_t zbytes = off;                              // zero everything above
  float* aS1 = (float*)alo((size_t)N * 4 * 4);      // direct-stored by GEMM (zero-overrun ok)
  float* aD1 = (float*)alo((size_t)N * 4 * 4);
  float* aS2 = (float*)alo((size_t)N * 4);
  float* aD2 = (float*)alo((size_t)N * 4);
  int* histT = (int*)alo((size_t)256 * 256 * 4);
  int* bexcl = (int*)alo((size_t)256 * 256 * 4);
  int* total = (int*)alo((size_t)256 * 4);
  int2* tmp = (int2*)alo((size_t)ET * 8);           // bucket-partitioned edges
  int2* epk = (int2*)alo((size_t)ET * 8);           // final dst-sorted (src,dst)
  __half* w1t = (__half*)alo((size_t)208 * F * 2);  // rows 0-191 W1^T, 192-197 W·att, 198-207 pad0
  __half* w2t = (__half*)alo((size_t)80 * HC * 2);  // rows 0-63 W2^T, 64-65 W·att, 66-79 pad0
  __half* xp1 = (__half*)alo((size_t)N * 192 * 2 + 512);  // +pad: DMA clamp overreach
  __half* xp2 = (__half*)alo((size_t)N * 64 * 2 + 512);

  // ---- prep (zero + hist + wt + W·att) -> scan -> partition -> [sort ∥ GEMM1] ----
  int zb = (int)((zbytes + 16383) / 16384);         // 16KB zero tiles (overrun into aS1 ok)
  int wtTot = F * HC + HC * LH;
  int wtb = (wtTot + 255) / 256;
  k_prep<<<zb + 256 + wtb + 3, 256, 0, stream>>>((float*)d_ws, zb, ei, E, ET, histT, NBK,
                                                 W1, w1t, W2, w2t, as1, ad1, as2, ad2,
                                                 F, HC, LH, wtb);
  k_scan1<<<NBK, 256, 0, stream>>>(histT, bexcl, total);
  k_part<<<256, 256, 0, stream>>>(ei, E, ET, bexcl, total, tmp, NBK);

  int mb = (N + 63) / 64;
  int wavesE = (ET + 63) / 64;
  int ebk = (wavesE + 3) / 4;

  // ---- fused: in-bucket dst-sort ∥ layer-1 GEMM (independent; one dispatch) ----
  k_scatgemm<128, 3, 0><<<NBK + mb, 256, 0, stream>>>(tmp, total, epk, NBK,
                                                      x, w1t, xp1, aS1, aD1,
                                                      nullptr, nullptr, 0, N, HC, 4);
  dim3 ge1(ebk, 3);
  k_aggE<3><<<ge1, 256, 0, stream>>>(epk, aS1, aD1, xp1, h1f, dnm1, ET, 192, 192, N);
  // ---- layer 2: MFMA GEMM (A = h1f/denom + bias + ELU) -> agg -> pool+final ----
  k_gemm_mfma<192, 1, 1><<<mb, 256, 0, stream>>>(h1f, w2t, xp2, aS2, aD2,
                                                 b1, dnm1, N, N, LH, 1);
  dim3 ge2(ebk, 1);
  k_aggE<1><<<ge2, 256, 0, stream>>>(epk, aS2, aD2, xp2, h2f, dnm2, ET, 64, 64, N);
  k_poolfinal<<<GRAPHS, 256, 0, stream>>>(h2f, dnm2, batch, b2, lw, lb, out, N);
}